// Round 6
// baseline (333.921 us; speedup 1.0000x reference)
//
#include <hip/hip_runtime.h>
#include <hip/hip_bf16.h>
#include <stdint.h>

typedef __bf16 bf16x8 __attribute__((ext_vector_type(8)));
typedef __bf16 bf16x4 __attribute__((ext_vector_type(4)));
typedef float f32x4 __attribute__((ext_vector_type(4)));

constexpr int S = 1024, Bsz = 16, Hd = 1024;
constexpr int M = S * Bsz;   // 16384
constexpr int N = 3 * Hd;    // 3072
constexpr int K = 1024;
constexpr int BM = 128, BN = 128, BK = 64;
constexpr int NCH = 32, CS = S / NCH;  // 32 chunks x 32 steps
constexpr int BH = Bsz * Hd;           // 16384
constexpr int NX8 = 2097152;           // X bf16x8 chunks
constexpr int NW8 = 393216;            // W bf16x8 chunks

__device__ __forceinline__ float fast_sigmoid(float x) { return 1.0f / (1.0f + __expf(-x)); }
__device__ __forceinline__ float fast_tanh(float x) { return 2.0f / (1.0f + __expf(-2.0f * x)) - 1.0f; }

// async global->LDS 16B per lane; LDS dest is wave-uniform base + lane*16
__device__ __forceinline__ void gld_lds16(const __bf16* g, __bf16* l) {
  __builtin_amdgcn_global_load_lds(
      (const __attribute__((address_space(1))) void*)g,
      (__attribute__((address_space(3))) void*)l,
      16, 0, 0);
}

// ---- fused fp32 -> bf16 conversion for X and W, 8 elems/thread ----
__global__ void convert_all(const float* __restrict__ X, const float* __restrict__ W,
                            __bf16* __restrict__ Xb, __bf16* __restrict__ Wb) {
  int i = blockIdx.x * 256 + threadIdx.x;
  const float* s;
  __bf16* d;
  int idx;
  if (i < NX8) { s = X; d = Xb; idx = i; }
  else if (i < NX8 + NW8) { s = W; d = Wb; idx = i - NX8; }
  else return;
  const float4* s4 = (const float4*)s;
  float4 a = s4[2 * idx], b = s4[2 * idx + 1];
  bf16x8 v;
  v[0] = (__bf16)a.x; v[1] = (__bf16)a.y; v[2] = (__bf16)a.z; v[3] = (__bf16)a.w;
  v[4] = (__bf16)b.x; v[5] = (__bf16)b.y; v[6] = (__bf16)b.z; v[7] = (__bf16)b.w;
  *((bf16x8*)d + idx) = v;
}

// ---- bf16 MFMA GEMM (NT: C[m,n] = sum_k A[m,k]*W[n,k]) + bias + activation ----
// 128x128 tile, BK=64, 256 threads (4 waves, 2x2 of 64x64), 16x16x32 MFMA.
// BK=64: 16 K-iters, 32 barrier drains (vs 64 at BK=32), 32 MFMA/wave per
// drain. LDS 32 KB: blocks/CU stays reg-limited at 3 (LDS allows 5) — the
// m132 BK=128 regression (64 KB -> 2 blocks) does not apply.
__global__ __launch_bounds__(256) void gemm_act(const __bf16* __restrict__ A,
                                                const __bf16* __restrict__ Bw,
                                                const float* __restrict__ bias,
                                                __bf16* __restrict__ Y) {
  __shared__ __align__(16) __bf16 As[BM * BK];  // 16 KB, flat: elem = row*64 + col
  __shared__ __align__(16) __bf16 Bs[BN * BK];  // 16 KB
  const int t = threadIdx.x;
  const int lane = t & 63;
  const int wave = t >> 6;
  const int wm = wave >> 1, wn = wave & 1;
  const int tn = blockIdx.x % (N / BN);
  const int tm = blockIdx.x / (N / BN);
  const int m0 = tm * BM, n0 = tn * BN;
  const int lrow = lane & 15;
  const int quad = lane >> 4;

  // staging: 1024 chunks of 16B per matrix; thread t handles chunks t+i*256.
  // chunk c -> LDS bytes c*16; row = c>>3, cw = c&7 (8 chunks per 64-elem row)
  const int srow = t >> 3;      // 0..31
  const int scw = t & 7;
  const __bf16* gA[4];
  const __bf16* gB[4];
  __bf16* lA[4];
  __bf16* lB[4];
#pragma unroll
  for (int i = 0; i < 4; ++i) {
    gA[i] = A + (size_t)(m0 + srow + i * 32) * K + scw * 8;
    gB[i] = Bw + (size_t)(n0 + srow + i * 32) * K + scw * 8;
    lA[i] = As + i * 2048 + wave * 512;  // wave-uniform base (elems)
    lB[i] = Bs + i * 2048 + wave * 512;
  }

  f32x4 acc[4][4] = {};

  for (int k0 = 0; k0 < K; k0 += BK) {
    __syncthreads();
#pragma unroll
    for (int i = 0; i < 4; ++i) {
      gld_lds16(gA[i], lA[i]);
      gld_lds16(gB[i], lB[i]);
    }
#pragma unroll
    for (int i = 0; i < 4; ++i) { gA[i] += BK; gB[i] += BK; }
    __syncthreads();

    // two K-substeps of 32; fragments loaded per substep to cap live VGPRs
#pragma unroll
    for (int s = 0; s < 2; ++s) {
      bf16x8 af[4], bfr[4];
#pragma unroll
      for (int mi = 0; mi < 4; ++mi)
        af[mi] = *(const bf16x8*)(&As[(wm * 64 + mi * 16 + lrow) * BK + s * 32 + quad * 8]);
#pragma unroll
      for (int ni = 0; ni < 4; ++ni)
        bfr[ni] = *(const bf16x8*)(&Bs[(wn * 64 + ni * 16 + lrow) * BK + s * 32 + quad * 8]);
#pragma unroll
      for (int mi = 0; mi < 4; ++mi)
#pragma unroll
        for (int ni = 0; ni < 4; ++ni)
          acc[mi][ni] = __builtin_amdgcn_mfma_f32_16x16x32_bf16(af[mi], bfr[ni], acc[mi][ni], 0, 0, 0);
    }
  }

  // epilogue: C/D layout col=lane&15, row=quad*4+reg (m89/m91-verified)
#pragma unroll
  for (int ni = 0; ni < 4; ++ni) {
    int col = n0 + wn * 64 + ni * 16 + lrow;
    float bv = bias[col];
    bool is_tanh = (col < Hd);
#pragma unroll
    for (int mi = 0; mi < 4; ++mi) {
#pragma unroll
      for (int r = 0; r < 4; ++r) {
        int m = m0 + wm * 64 + mi * 16 + quad * 4 + r;
        float y = acc[mi][ni][r] + bv;
        float v = is_tanh ? fast_tanh(y) : fast_sigmoid(y);
        Y[(size_t)m * N + col] = (__bf16)v;
      }
    }
  }
}

// ---- chunked affine scan, 4-wide over h (512 blocks = 2 blocks/CU) ----
// pass1: per-chunk composition (A,B): h_out = A*h_in + B
__global__ __launch_bounds__(256) void scan_pass1(const __bf16* __restrict__ Y,
                                                  float* __restrict__ Ac,
                                                  float* __restrict__ Bc) {
  int tid = blockIdx.x * 256 + threadIdx.x;  // 0..131071
  int c = tid >> 12;
  int bh4 = tid & 4095;
  int b = bh4 >> 8, h0 = (bh4 & 255) * 4;
  const size_t sstep = (size_t)Bsz * N;
  const __bf16* base = Y + (size_t)(c * CS) * sstep + (size_t)b * N + h0;
  float A[4], Bv[4];
#pragma unroll
  for (int l = 0; l < 4; ++l) { A[l] = 1.0f; Bv[l] = 0.0f; }
  for (int j0 = 0; j0 < CS; j0 += 8) {
    bf16x4 z[8], f[8];
#pragma unroll
    for (int j = 0; j < 8; ++j) {
      const __bf16* p = base + (size_t)(j0 + j) * sstep;
      z[j] = *(const bf16x4*)p;
      f[j] = *(const bf16x4*)(p + Hd);
    }
#pragma unroll
    for (int j = 0; j < 8; ++j)
#pragma unroll
      for (int l = 0; l < 4; ++l) {
        float ff = (float)f[j][l];
        float a = 1.0f - ff;
        Bv[l] = fmaf(a, Bv[l], ff * (float)z[j][l]);
        A[l] *= a;
      }
  }
  int ob = c * BH + b * Hd + h0;
#pragma unroll
  for (int l = 0; l < 4; ++l) { Ac[ob + l] = A[l]; Bc[ob + l] = Bv[l]; }
}

// pass2: chain chunk states; emit per-chunk h_in and C_last
__global__ __launch_bounds__(256) void scan_pass2(const float* __restrict__ Ac,
                                                  const float* __restrict__ Bc,
                                                  float* __restrict__ hin,
                                                  float* __restrict__ clast) {
  int bh = blockIdx.x * 256 + threadIdx.x;  // 0..BH-1
  float h = 0.0f;
#pragma unroll 4
  for (int c = 0; c < NCH; ++c) {
    hin[c * BH + bh] = h;
    h = fmaf(Ac[c * BH + bh], h, Bc[c * BH + bh]);
  }
  clast[bh] = h;
}

// pass3: replay chunk from known h_in, write Hout = o * h (float4 stores)
__global__ __launch_bounds__(256) void scan_pass3(const __bf16* __restrict__ Y,
                                                  const float* __restrict__ hin,
                                                  float* __restrict__ hout) {
  int tid = blockIdx.x * 256 + threadIdx.x;  // 0..131071
  int c = tid >> 12;
  int bh4 = tid & 4095;
  int b = bh4 >> 8, h0 = (bh4 & 255) * 4;
  const size_t sstep = (size_t)Bsz * N;
  const __bf16* base = Y + (size_t)(c * CS) * sstep + (size_t)b * N + h0;
  float* ob = hout + (size_t)(c * CS) * BH + (size_t)b * Hd + h0;
  float hp[4];
  int hb = c * BH + b * Hd + h0;
#pragma unroll
  for (int l = 0; l < 4; ++l) hp[l] = hin[hb + l];
  for (int j0 = 0; j0 < CS; j0 += 4) {
    bf16x4 z[4], f[4], o[4];
#pragma unroll
    for (int j = 0; j < 4; ++j) {
      const __bf16* p = base + (size_t)(j0 + j) * sstep;
      z[j] = *(const bf16x4*)p;
      f[j] = *(const bf16x4*)(p + Hd);
      o[j] = *(const bf16x4*)(p + 2 * Hd);
    }
#pragma unroll
    for (int j = 0; j < 4; ++j) {
      float out4[4];
#pragma unroll
      for (int l = 0; l < 4; ++l) {
        float ff = (float)f[j][l];
        hp[l] = fmaf(ff, (float)z[j][l] - hp[l], hp[l]);  // f*z + (1-f)*h
        out4[l] = (float)o[j][l] * hp[l];
      }
      *(float4*)(ob + (size_t)(j0 + j) * BH) = make_float4(out4[0], out4[1], out4[2], out4[3]);
    }
  }
}

extern "C" void kernel_launch(void* const* d_in, const int* in_sizes, int n_in,
                              void* d_out, int out_size, void* d_ws, size_t ws_size,
                              hipStream_t stream) {
  const float* X = (const float*)d_in[0];    // [1024,16,1024]
  const float* W = (const float*)d_in[1];    // [3072,1024]
  const float* bias = (const float*)d_in[2]; // [3072]
  float* out = (float*)d_out;                // Hout (16777216) + C_last (16384)

  char* ws = (char*)d_ws;
  __bf16* Xb = (__bf16*)ws;                      // 33,554,432 B
  __bf16* Wb = (__bf16*)(ws + 33554432);         // 6,291,456 B
  __bf16* Yv = (__bf16*)(ws + 39845888);         // 100,663,296 B (bf16 Y)
  float* Ac = (float*)(ws + 39845888 + 100663296);
  float* Bc = Ac + NCH * BH;                     // 2 MB each
  float* hin = Bc + NCH * BH;

  convert_all<<<(NX8 + NW8) / 256, 256, 0, stream>>>(X, W, Xb, Wb);

  dim3 ggrid((M / BM) * (N / BN));  // 3072
  dim3 sgrid(NCH * BH / 4 / 256);   // 512
  gemm_act<<<ggrid, 256, 0, stream>>>(Xb, Wb, bias, Yv);
  scan_pass1<<<sgrid, 256, 0, stream>>>(Yv, Ac, Bc);
  scan_pass2<<<BH / 256, 256, 0, stream>>>(Ac, Bc, hin, out + 16777216);
  scan_pass3<<<sgrid, 256, 0, stream>>>(Yv, hin, out);
}

// Round 7
// 326.572 us; speedup vs baseline: 1.0225x; 1.0225x over previous
//
#include <hip/hip_runtime.h>
#include <hip/hip_bf16.h>
#include <stdint.h>

typedef __bf16 bf16x8 __attribute__((ext_vector_type(8)));
typedef __bf16 bf16x4 __attribute__((ext_vector_type(4)));
typedef float f32x4 __attribute__((ext_vector_type(4)));
typedef float f32x16 __attribute__((ext_vector_type(16)));

constexpr int S = 1024, Bsz = 16, Hd = 1024;
constexpr int M = S * Bsz;   // 16384
constexpr int N = 3 * Hd;    // 3072
constexpr int K = 1024;
constexpr int BM = 128, BN = 128, BK = 32;
constexpr int NCH = 32, CS = S / NCH;  // 32 chunks x 32 steps
constexpr int BH = Bsz * Hd;           // 16384
constexpr int NX8 = 2097152;           // X bf16x8 chunks
constexpr int NW8 = 393216;            // W bf16x8 chunks

__device__ __forceinline__ float fast_sigmoid(float x) { return 1.0f / (1.0f + __expf(-x)); }
__device__ __forceinline__ float fast_tanh(float x) { return 2.0f / (1.0f + __expf(-2.0f * x)) - 1.0f; }

// async global->LDS 16B per lane; LDS dest is wave-uniform base + lane*16
__device__ __forceinline__ void gld_lds16(const __bf16* g, __bf16* l) {
  __builtin_amdgcn_global_load_lds(
      (const __attribute__((address_space(1))) void*)g,
      (__attribute__((address_space(3))) void*)l,
      16, 0, 0);
}

// ---- fused fp32 -> bf16 conversion for X and W, 8 elems/thread ----
__global__ void convert_all(const float* __restrict__ X, const float* __restrict__ W,
                            __bf16* __restrict__ Xb, __bf16* __restrict__ Wb) {
  int i = blockIdx.x * 256 + threadIdx.x;
  const float* s;
  __bf16* d;
  int idx;
  if (i < NX8) { s = X; d = Xb; idx = i; }
  else if (i < NX8 + NW8) { s = W; d = Wb; idx = i - NX8; }
  else return;
  const float4* s4 = (const float4*)s;
  float4 a = s4[2 * idx], b = s4[2 * idx + 1];
  bf16x8 v;
  v[0] = (__bf16)a.x; v[1] = (__bf16)a.y; v[2] = (__bf16)a.z; v[3] = (__bf16)a.w;
  v[4] = (__bf16)b.x; v[5] = (__bf16)b.y; v[6] = (__bf16)b.z; v[7] = (__bf16)b.w;
  *((bf16x8*)d + idx) = v;
}

// ---- bf16 MFMA GEMM (NT) + bias + activation, 32x32x16 MFMA ----
// 128x128 tile, BK=32 (64 B row stride — optimal bank spread), 256 threads
// (4 waves, 2x2 of 64x64; each wave 2x2 of 32x32 MFMAs). 8 MFMA/iter/wave
// (8.07 cyc each) vs 16 (4.85) for 16x16 — 17% less matrix-pipe time.
// XOR chunk swizzle p = cw ^ ((row>>1)&3) applied on the GLOBAL source side
// (LDS writes stay lane-contiguous per global_load_lds constraint); restores
// full 32-bank spread for the lane&31-row fragment reads.
__global__ __launch_bounds__(256) void gemm_act(const __bf16* __restrict__ A,
                                                const __bf16* __restrict__ Bw,
                                                const float* __restrict__ bias,
                                                __bf16* __restrict__ Y) {
  __shared__ __align__(16) __bf16 As[BM * BK];  // 8 KB; (row,slot p): bytes row*64 + p*16
  __shared__ __align__(16) __bf16 Bs[BN * BK];  // 8 KB
  const int t = threadIdx.x;
  const int lane = t & 63;
  const int wave = t >> 6;
  const int wm = wave >> 1, wn = wave & 1;
  const int tn = blockIdx.x % (N / BN);
  const int tm = blockIdx.x / (N / BN);
  const int m0 = tm * BM, n0 = tn * BN;
  const int l32 = lane & 31;          // fragment row within 32-tile
  const int khalf = lane >> 5;        // 0/1: k-subchunk selector

  // staging: chunk c = t + i*256; row = c>>2, slot = c&3.
  // stored logical cw = slot ^ swz(row), swz(r) = (r>>1)&3 (same for row, row+64)
  const int srow = t >> 2;            // 0..63
  const int sswz = (srow >> 1) & 3;
  const int cw_log = (t & 3) ^ sswz;
  const __bf16* gA0 = A + (size_t)(m0 + srow) * K + cw_log * 8;
  const __bf16* gA1 = gA0 + (size_t)64 * K;
  const __bf16* gB0 = Bw + (size_t)(n0 + srow) * K + cw_log * 8;
  const __bf16* gB1 = gB0 + (size_t)64 * K;
  __bf16* lA0 = As + wave * 512;      // wave-uniform bases (elems)
  __bf16* lA1 = As + 2048 + wave * 512;
  __bf16* lB0 = Bs + wave * 512;
  __bf16* lB1 = Bs + 2048 + wave * 512;

  const int rswz = (l32 >> 1) & 3;    // swz of fragment row (row%32 == l32)

  f32x16 acc[2][2] = {};

  for (int k0 = 0; k0 < K; k0 += BK) {
    __syncthreads();
    gld_lds16(gA0, lA0);
    gld_lds16(gA1, lA1);
    gld_lds16(gB0, lB0);
    gld_lds16(gB1, lB1);
    gA0 += BK; gA1 += BK; gB0 += BK; gB1 += BK;
    __syncthreads();

    // A[m=l32][k=khalf*8+j], B[n=l32][k=khalf*8+j]; two K=16 substeps
#pragma unroll
    for (int s = 0; s < 2; ++s) {
      const int p = (s * 2 + khalf) ^ rswz;  // physical 16B slot
      bf16x8 af[2], bfr[2];
#pragma unroll
      for (int mi = 0; mi < 2; ++mi)
        af[mi] = *(const bf16x8*)(&As[(wm * 64 + mi * 32 + l32) * BK + p * 8]);
#pragma unroll
      for (int ni = 0; ni < 2; ++ni)
        bfr[ni] = *(const bf16x8*)(&Bs[(wn * 64 + ni * 32 + l32) * BK + p * 8]);
#pragma unroll
      for (int mi = 0; mi < 2; ++mi)
#pragma unroll
        for (int ni = 0; ni < 2; ++ni)
          acc[mi][ni] = __builtin_amdgcn_mfma_f32_32x32x16_bf16(af[mi], bfr[ni], acc[mi][ni], 0, 0, 0);
    }
  }

  // epilogue: 32x32 C/D layout col=lane&31, row=(reg&3)+8*(reg>>2)+4*(lane>>5)
  // (m74/m101-verified, dtype-independent)
#pragma unroll
  for (int ni = 0; ni < 2; ++ni) {
    int col = n0 + wn * 64 + ni * 32 + l32;
    float bv = bias[col];
    bool is_tanh = (col < Hd);
#pragma unroll
    for (int mi = 0; mi < 2; ++mi) {
#pragma unroll
      for (int reg = 0; reg < 16; ++reg) {
        int m = m0 + wm * 64 + mi * 32 + (reg & 3) + 8 * (reg >> 2) + 4 * khalf;
        float y = acc[mi][ni][reg] + bv;
        float v = is_tanh ? fast_tanh(y) : fast_sigmoid(y);
        Y[(size_t)m * N + col] = (__bf16)v;
      }
    }
  }
}

// ---- chunked affine scan, 4-wide over h (512 blocks = 2 blocks/CU) ----
// pass1: per-chunk composition (A,B): h_out = A*h_in + B
__global__ __launch_bounds__(256) void scan_pass1(const __bf16* __restrict__ Y,
                                                  float* __restrict__ Ac,
                                                  float* __restrict__ Bc) {
  int tid = blockIdx.x * 256 + threadIdx.x;  // 0..131071
  int c = tid >> 12;
  int bh4 = tid & 4095;
  int b = bh4 >> 8, h0 = (bh4 & 255) * 4;
  const size_t sstep = (size_t)Bsz * N;
  const __bf16* base = Y + (size_t)(c * CS) * sstep + (size_t)b * N + h0;
  float A[4], Bv[4];
#pragma unroll
  for (int l = 0; l < 4; ++l) { A[l] = 1.0f; Bv[l] = 0.0f; }
  for (int j0 = 0; j0 < CS; j0 += 8) {
    bf16x4 z[8], f[8];
#pragma unroll
    for (int j = 0; j < 8; ++j) {
      const __bf16* p = base + (size_t)(j0 + j) * sstep;
      z[j] = *(const bf16x4*)p;
      f[j] = *(const bf16x4*)(p + Hd);
    }
#pragma unroll
    for (int j = 0; j < 8; ++j)
#pragma unroll
      for (int l = 0; l < 4; ++l) {
        float ff = (float)f[j][l];
        float a = 1.0f - ff;
        Bv[l] = fmaf(a, Bv[l], ff * (float)z[j][l]);
        A[l] *= a;
      }
  }
  int ob = c * BH + b * Hd + h0;
#pragma unroll
  for (int l = 0; l < 4; ++l) { Ac[ob + l] = A[l]; Bc[ob + l] = Bv[l]; }
}

// pass2: chain chunk states; emit per-chunk h_in and C_last
__global__ __launch_bounds__(256) void scan_pass2(const float* __restrict__ Ac,
                                                  const float* __restrict__ Bc,
                                                  float* __restrict__ hin,
                                                  float* __restrict__ clast) {
  int bh = blockIdx.x * 256 + threadIdx.x;  // 0..BH-1
  float h = 0.0f;
#pragma unroll 4
  for (int c = 0; c < NCH; ++c) {
    hin[c * BH + bh] = h;
    h = fmaf(Ac[c * BH + bh], h, Bc[c * BH + bh]);
  }
  clast[bh] = h;
}

// pass3: replay chunk from known h_in, write Hout = o * h (float4 stores)
__global__ __launch_bounds__(256) void scan_pass3(const __bf16* __restrict__ Y,
                                                  const float* __restrict__ hin,
                                                  float* __restrict__ hout) {
  int tid = blockIdx.x * 256 + threadIdx.x;  // 0..131071
  int c = tid >> 12;
  int bh4 = tid & 4095;
  int b = bh4 >> 8, h0 = (bh4 & 255) * 4;
  const size_t sstep = (size_t)Bsz * N;
  const __bf16* base = Y + (size_t)(c * CS) * sstep + (size_t)b * N + h0;
  float* ob = hout + (size_t)(c * CS) * BH + (size_t)b * Hd + h0;
  float hp[4];
  int hb = c * BH + b * Hd + h0;
#pragma unroll
  for (int l = 0; l < 4; ++l) hp[l] = hin[hb + l];
  for (int j0 = 0; j0 < CS; j0 += 4) {
    bf16x4 z[4], f[4], o[4];
#pragma unroll
    for (int j = 0; j < 4; ++j) {
      const __bf16* p = base + (size_t)(j0 + j) * sstep;
      z[j] = *(const bf16x4*)p;
      f[j] = *(const bf16x4*)(p + Hd);
      o[j] = *(const bf16x4*)(p + 2 * Hd);
    }
#pragma unroll
    for (int j = 0; j < 4; ++j) {
      float out4[4];
#pragma unroll
      for (int l = 0; l < 4; ++l) {
        float ff = (float)f[j][l];
        hp[l] = fmaf(ff, (float)z[j][l] - hp[l], hp[l]);  // f*z + (1-f)*h
        out4[l] = (float)o[j][l] * hp[l];
      }
      *(float4*)(ob + (size_t)(j0 + j) * BH) = make_float4(out4[0], out4[1], out4[2], out4[3]);
    }
  }
}

extern "C" void kernel_launch(void* const* d_in, const int* in_sizes, int n_in,
                              void* d_out, int out_size, void* d_ws, size_t ws_size,
                              hipStream_t stream) {
  const float* X = (const float*)d_in[0];    // [1024,16,1024]
  const float* W = (const float*)d_in[1];    // [3072,1024]
  const float* bias = (const float*)d_in[2]; // [3072]
  float* out = (float*)d_out;                // Hout (16777216) + C_last (16384)

  char* ws = (char*)d_ws;
  __bf16* Xb = (__bf16*)ws;                      // 33,554,432 B
  __bf16* Wb = (__bf16*)(ws + 33554432);         // 6,291,456 B
  __bf16* Yv = (__bf16*)(ws + 39845888);         // 100,663,296 B (bf16 Y)
  float* Ac = (float*)(ws + 39845888 + 100663296);
  float* Bc = Ac + NCH * BH;                     // 2 MB each
  float* hin = Bc + NCH * BH;

  convert_all<<<(NX8 + NW8) / 256, 256, 0, stream>>>(X, W, Xb, Wb);

  dim3 ggrid((M / BM) * (N / BN));  // 3072
  dim3 sgrid(NCH * BH / 4 / 256);   // 512
  gemm_act<<<ggrid, 256, 0, stream>>>(Xb, Wb, bias, Yv);
  scan_pass1<<<sgrid, 256, 0, stream>>>(Yv, Ac, Bc);
  scan_pass2<<<BH / 256, 256, 0, stream>>>(Ac, Bc, hin, out + 16777216);
  scan_pass3<<<sgrid, 256, 0, stream>>>(Yv, hin, out);
}